// Round 6
// baseline (855.391 us; speedup 1.0000x reference)
//
#include <hip/hip_runtime.h>
#include <hip/hip_bf16.h>
#include <hip/hip_fp16.h>
#include <math.h>

#define NN 100000
#define EE 800000

static constexpr int SCAN_CH = 512;
static constexpr int NCH = (NN + SCAN_CH - 1) / SCAN_CH; // 196

__device__ __forceinline__ float leaky(float a) { return a >= 0.0f ? a : 0.2f * a; }
__device__ __forceinline__ float quantize(float v, float s) {
    float r = rintf(v / s);
    r = fminf(fmaxf(r, -128.0f), 127.0f);
    return r * s;
}

// ---------------- init: zero counters ----------------
__global__ void k_init(unsigned* deg_src, unsigned* deg_dst, unsigned* s1, unsigned* s2) {
    int i = blockIdx.x * 256 + threadIdx.x;
    if (i < NN) { deg_src[i] = 0; deg_dst[i] = 0; }
    if (i < 256) { s1[i] = 0; s2[i] = 0; }
}

// ---------------- degree count ----------------
__global__ void k_deg(const int* ei, unsigned* deg_src, unsigned* deg_dst) {
    int e = blockIdx.x * 256 + threadIdx.x;
    if (e < EE) {
        atomicAdd(&deg_src[ei[e]], 1u);
        atomicAdd(&deg_dst[ei[EE + e]], 1u);
    }
}

// ---------------- scan (3 kernels) ----------------
__global__ void k_scan_chunksum(const unsigned* deg_dst, unsigned* chunkSum) {
    __shared__ unsigned red[256];
    int b = blockIdx.x, t = threadIdx.x;
    int g0 = b * SCAN_CH + t;
    unsigned v = 0;
    if (g0 < NN) v += deg_dst[g0];
    if (g0 + 256 < NN && t + 256 < SCAN_CH) v += deg_dst[g0 + 256];
    red[t] = v; __syncthreads();
    for (int s = 128; s > 0; s >>= 1) { if (t < s) red[t] += red[t + s]; __syncthreads(); }
    if (t == 0) chunkSum[b] = red[0];
}

__global__ void k_scan_chunkoff(const unsigned* chunkSum, unsigned* chunkOff, unsigned* off) {
    __shared__ unsigned sc[256];
    int t = threadIdx.x;
    unsigned v = (t < NCH) ? chunkSum[t] : 0u;
    sc[t] = v; __syncthreads();
    for (int d = 1; d < 256; d <<= 1) {
        unsigned add = (t >= d) ? sc[t - d] : 0u; __syncthreads();
        sc[t] += add; __syncthreads();
    }
    if (t < NCH) chunkOff[t] = sc[t] - v;
    if (t == 255) off[NN] = sc[255];
}

// final scan + cursor init + degree-norm tables (fused)
__global__ void k_scan_final(const unsigned* deg_dst, const unsigned* chunkOff,
                             unsigned* off, unsigned* cursor,
                             const unsigned* deg_src, const float* a1p, const float* a2p,
                             float* rn1, float* rn2) {
    __shared__ unsigned sc[256];
    int b = blockIdx.x, t = threadIdx.x;
    int g0 = b * SCAN_CH + 2 * t;
    unsigned a = (g0 < NN) ? deg_dst[g0] : 0u;
    unsigned c = (g0 + 1 < NN) ? deg_dst[g0 + 1] : 0u;
    unsigned ps = a + c;
    sc[t] = ps; __syncthreads();
    for (int d = 1; d < 256; d <<= 1) {
        unsigned add = (t >= d) ? sc[t - d] : 0u; __syncthreads();
        sc[t] += add; __syncthreads();
    }
    unsigned base = chunkOff[b] + sc[t] - ps;
    float e1 = -a1p[0], e2 = -a2p[0];
    if (g0 < NN) {
        off[g0] = base; cursor[g0] = base;
        float d0 = (float)deg_src[g0] + 1.0f;
        rn1[g0] = powf(d0, e1); rn2[g0] = powf(d0, e2);
    }
    if (g0 + 1 < NN) {
        off[g0 + 1] = base + a; cursor[g0 + 1] = base + a;
        float d1 = (float)deg_src[g0 + 1] + 1.0f;
        rn1[g0 + 1] = powf(d1, e1); rn2[g0 + 1] = powf(d1, e2);
    }
}

// ---------------- scatter: sort edges by dst ----------------
__global__ void k_scatter(const int* ei, unsigned* cursor, unsigned* pos_of_edge,
                          unsigned* src_sorted) {
    int e = blockIdx.x * 256 + threadIdx.x;
    if (e < EE) {
        int d = ei[EE + e];
        unsigned pos = atomicAdd(&cursor[d], 1u);
        pos_of_edge[e] = pos;
        src_sorted[pos] = (unsigned)ei[e];
    }
}

// ---------------- weight fake-quant + a_edge projection vectors ----------------
// block 0: layer 1, block 1: layer 2
__global__ void k_weights(const float* W1, const float* W2,
                          const float* We1, const float* ae1,
                          const float* We2, const float* ae2,
                          float* Wq1, float* Wq2, float* v1, float* v2) {
    __shared__ float red[256];
    int t = threadIdx.x;
    const float* W  = blockIdx.x ? W2 : W1;
    const float* We = blockIdx.x ? We2 : We1;
    const float* ae = blockIdx.x ? ae2 : ae1;
    float* Wq = blockIdx.x ? Wq2 : Wq1;
    float* v  = blockIdx.x ? v2 : v1;
    float m = 0.0f;
    for (int i = t; i < 8192; i += 256) m = fmaxf(m, fabsf(W[i]));
    red[t] = m; __syncthreads();
    for (int s = 128; s > 0; s >>= 1) { if (t < s) red[t] = fmaxf(red[t], red[t + s]); __syncthreads(); }
    float s1 = fmaxf(red[0], 1e-8f) / 127.0f;
    __syncthreads();
    for (int i = t; i < 8192; i += 256) Wq[i] = quantize(W[i], s1);
    if (t < 64) {
        int h = t >> 5, d = t & 31;
        float acc = 0.0f;
        for (int c = 0; c < 64; ++c) acc += We[(h * 64 + c) * 32 + d] * ae[h * 64 + c];
        v[t] = acc;
    }
}

// ---------------- a_edge for both layers, scattered into dst-sorted order ----------------
__global__ void k_aedge(const float* edge_attr, const float* v1, const float* v2,
                        const unsigned* pos_of_edge, float2* ae1s, float2* ae2s) {
    __shared__ float vs[128];
    int t = threadIdx.x;
    if (t < 64) vs[t] = v1[t];
    else if (t < 128) vs[t] = v2[t - 64];
    __syncthreads();
    int e = blockIdx.x * 256 + t;
    if (e >= EE) return;
    const float4* ea = (const float4*)(edge_attr + (size_t)e * 32);
    float a00 = 0, a01 = 0, a10 = 0, a11 = 0;
#pragma unroll
    for (int q = 0; q < 8; ++q) {
        float4 w = ea[q];
        float xs4[4] = {w.x, w.y, w.z, w.w};
#pragma unroll
        for (int j = 0; j < 4; ++j) {
            int d = q * 4 + j;
            a00 += xs4[j] * vs[d];
            a01 += xs4[j] * vs[32 + d];
            a10 += xs4[j] * vs[64 + d];
            a11 += xs4[j] * vs[96 + d];
        }
    }
    unsigned pos = pos_of_edge[e];
    ae1s[pos] = make_float2(a00, a01);
    ae2s[pos] = make_float2(a10, a11);
}

// ---------------- h = f(in) @ Wq.T (+ a_src/a_dst dots), h stored fp16 ----------------
// slots==nullptr: f = rn-scale (layer 1).  slots!=nullptr: f = rn2*relu(quant(v,s1)) (layer 2).
__global__ void __launch_bounds__(256, 2)
k_hproj(const float* __restrict__ in, const float* __restrict__ rn,
        const unsigned* __restrict__ slots,
        const float* __restrict__ Wq,
        const float* __restrict__ att_s, const float* __restrict__ att_d,
        __half2* __restrict__ hp, float2* __restrict__ asrcv,
        float2* __restrict__ adstv) {
    __shared__ float xs[32][64];   // 8 KB
    __shared__ unsigned redu[256];
    int t = threadIdx.x;
    float qs = 0.0f;
    if (slots) {   // fused absmax-slot reduction -> s1
        redu[t] = slots[t]; __syncthreads();
        for (int s = 128; s > 0; s >>= 1) {
            if (t < s) redu[t] = (redu[t] > redu[t + s]) ? redu[t] : redu[t + s];
            __syncthreads();
        }
        qs = fmaxf(__uint_as_float(redu[0]), 1e-8f) / 127.0f;
        __syncthreads();
    }
    int node0 = blockIdx.x * 32;
    for (int i = t; i < 512; i += 256) {
        int n = i >> 4, c4 = i & 15;
        int node = node0 + n;
        float4 v = make_float4(0.f, 0.f, 0.f, 0.f);
        if (node < NN) {
            v = ((const float4*)(in + (size_t)node * 64))[c4];
            float r = rn[node];
            if (slots) {
                v.x = fmaxf(quantize(v.x, qs), 0.f) * r;
                v.y = fmaxf(quantize(v.y, qs), 0.f) * r;
                v.z = fmaxf(quantize(v.z, qs), 0.f) * r;
                v.w = fmaxf(quantize(v.w, qs), 0.f) * r;
            } else {
                v.x *= r; v.y *= r; v.z *= r; v.w *= r;
            }
        }
        ((float4*)xs[n])[c4] = v;
    }
    int w = t >> 6, l = t & 63;
    float4 w0[16], w1[16];
    const float4* wp0 = (const float4*)(Wq + (size_t)l * 64);
    const float4* wp1 = (const float4*)(Wq + (size_t)(64 + l) * 64);
#pragma unroll
    for (int q = 0; q < 16; ++q) { w0[q] = wp0[q]; w1[q] = wp1[q]; }
    float as0 = att_s[l], as1 = att_s[64 + l];
    float ad0 = att_d[l], ad1 = att_d[64 + l];
    __syncthreads();
    for (int nn = 0; nn < 8; ++nn) {
        int node = node0 + w * 8 + nn;
        if (node >= NN) break;
        const float4* xr = (const float4*)xs[w * 8 + nn];
        float a0 = 0.0f, a1 = 0.0f;
#pragma unroll
        for (int q = 0; q < 16; ++q) {
            float4 xv = xr[q];             // uniform address -> LDS broadcast
            a0 += xv.x * w0[q].x + xv.y * w0[q].y + xv.z * w0[q].z + xv.w * w0[q].w;
            a1 += xv.x * w1[q].x + xv.y * w1[q].y + xv.z * w1[q].z + xv.w * w1[q].w;
        }
        hp[(size_t)node * 64 + l] = __floats2half2_rn(a0, a1);
        float ps0 = a0 * as0, ps1 = a1 * as1, pd0 = a0 * ad0, pd1 = a1 * ad1;
#pragma unroll
        for (int m = 32; m > 0; m >>= 1) {
            ps0 += __shfl_xor(ps0, m, 64);
            ps1 += __shfl_xor(ps1, m, 64);
            pd0 += __shfl_xor(pd0, m, 64);
            pd1 += __shfl_xor(pd1, m, 64);
        }
        if (l == 0) {
            asrcv[node] = make_float2(ps0, ps1);
            adstv[node] = make_float2(pd0, pd1);
        }
    }
}

// ---------------- fused softmax+aggregate: wave per dst node ----------------
// Phase 1 (lane-parallel): lanes l<deg load src + sorted-ae stream + asrcv gather, p = exp(leaky)
// Phase 2 (broadcast): readlane (src, p); 4 independent fp16 hp-row gathers per group.
__global__ void k_aggregate(const unsigned* __restrict__ off, const unsigned* __restrict__ src_s,
                            const float2* __restrict__ aes,
                            const float2* __restrict__ asrcv, const float2* __restrict__ adstv,
                            const __half2* __restrict__ hp, const float* __restrict__ bias,
                            float* __restrict__ outp, unsigned* __restrict__ amax_slots) {
    int t = threadIdx.x;
    int l = t & 63;
    int node = blockIdx.x * 4 + (t >> 6);
    if (node >= NN) return;
    unsigned s0 = off[node], e0 = off[node + 1];
    float2 adv = adstv[node];
    float acc0 = 0.f, acc1 = 0.f, psum0 = 0.f, psum1 = 0.f;
    for (unsigned base = s0; base < e0; base += 64) {
        int cnt = (int)min(64u, e0 - base);
        float p0 = 0.f, p1 = 0.f;
        unsigned s = 0u;
        if (l < cnt) {
            s = src_s[base + l];                 // coalesced
            float2 ev = aes[base + l];           // coalesced (dst-sorted stream)
            float2 av = asrcv[s];                // parallel 8B gather
            p0 = __expf(leaky(av.x + adv.x + ev.x));
            p1 = __expf(leaky(av.y + adv.y + ev.y));
        }
        psum0 += p0; psum1 += p1;
        int su = (int)s;
        unsigned pu0 = __float_as_uint(p0), pu1 = __float_as_uint(p1);
        for (int j = 0; j < cnt; j += 4) {
            unsigned sa = (unsigned)__builtin_amdgcn_readlane(su, j);
            unsigned sb = (unsigned)__builtin_amdgcn_readlane(su, j + 1);
            unsigned sc = (unsigned)__builtin_amdgcn_readlane(su, j + 2);
            unsigned sd = (unsigned)__builtin_amdgcn_readlane(su, j + 3);
            __half2 ha = hp[(size_t)sa * 64 + l];
            __half2 hb = hp[(size_t)sb * 64 + l];
            __half2 hc = hp[(size_t)sc * 64 + l];
            __half2 hd = hp[(size_t)sd * 64 + l];
            float qa0 = __uint_as_float((unsigned)__builtin_amdgcn_readlane((int)pu0, j));
            float qa1 = __uint_as_float((unsigned)__builtin_amdgcn_readlane((int)pu1, j));
            float qb0 = __uint_as_float((unsigned)__builtin_amdgcn_readlane((int)pu0, j + 1));
            float qb1 = __uint_as_float((unsigned)__builtin_amdgcn_readlane((int)pu1, j + 1));
            float qc0 = __uint_as_float((unsigned)__builtin_amdgcn_readlane((int)pu0, j + 2));
            float qc1 = __uint_as_float((unsigned)__builtin_amdgcn_readlane((int)pu1, j + 2));
            float qd0 = __uint_as_float((unsigned)__builtin_amdgcn_readlane((int)pu0, j + 3));
            float qd1 = __uint_as_float((unsigned)__builtin_amdgcn_readlane((int)pu1, j + 3));
            float2 fa = __half22float2(ha), fb = __half22float2(hb);
            float2 fc = __half22float2(hc), fd = __half22float2(hd);
            acc0 = fmaf(qa0, fa.x, fmaf(qb0, fb.x, fmaf(qc0, fc.x, fmaf(qd0, fd.x, acc0))));
            acc1 = fmaf(qa1, fa.y, fmaf(qb1, fb.y, fmaf(qc1, fc.y, fmaf(qd1, fd.y, acc1))));
        }
    }
#pragma unroll
    for (int m = 32; m > 0; m >>= 1) {
        psum0 += __shfl_xor(psum0, m, 64);
        psum1 += __shfl_xor(psum1, m, 64);
    }
    float o = 0.5f * (acc0 / (psum0 + 1e-16f) + acc1 / (psum1 + 1e-16f)) + bias[l];
    outp[(size_t)node * 64 + l] = o;
    float v = fabsf(o);
#pragma unroll
    for (int m = 32; m > 0; m >>= 1) v = fmaxf(v, __shfl_xor(v, m, 64));
    if (l == 0) atomicMax(&amax_slots[node & 255], __float_as_uint(v));
}

// ---------------- final output fake-quant in place (fused slot reduce) ----------------
__global__ void k_quant_out(float* buf, const unsigned* slots) {
    __shared__ unsigned red[256];
    int t = threadIdx.x;
    red[t] = slots[t]; __syncthreads();
    for (int s = 128; s > 0; s >>= 1) {
        if (t < s) red[t] = (red[t] > red[t + s]) ? red[t] : red[t + s];
        __syncthreads();
    }
    float s2 = fmaxf(__uint_as_float(red[0]), 1e-8f) / 127.0f;
    int i = blockIdx.x * 256 + t;
    if (i < NN * 64) buf[i] = quantize(buf[i], s2);
}

extern "C" void kernel_launch(void* const* d_in, const int* in_sizes, int n_in,
                              void* d_out, int out_size, void* d_ws, size_t ws_size,
                              hipStream_t stream) {
    const float* x     = (const float*)d_in[0];
    const int*   ei    = (const int*)d_in[1];
    const float* eattr = (const float*)d_in[2];
    const float* a1    = (const float*)d_in[3];
    const float* W1    = (const float*)d_in[4];
    const float* We1   = (const float*)d_in[5];
    const float* as1   = (const float*)d_in[6];
    const float* ad1   = (const float*)d_in[7];
    const float* ae1   = (const float*)d_in[8];
    const float* b1    = (const float*)d_in[9];
    const float* a2    = (const float*)d_in[10];
    const float* W2    = (const float*)d_in[11];
    const float* We2   = (const float*)d_in[12];
    const float* as2   = (const float*)d_in[13];
    const float* ad2   = (const float*)d_in[14];
    const float* ae2   = (const float*)d_in[15];
    const float* b2    = (const float*)d_in[16];
    float* out = (float*)d_out;

    char* w = (char*)d_ws;
    size_t o = 0;
    auto alloc = [&](size_t bytes) -> char* {
        char* p = w + o;
        o += (bytes + 255) & ~(size_t)255;
        return p;
    };
    unsigned* deg_src  = (unsigned*)alloc((size_t)NN * 4);
    unsigned* deg_dst  = (unsigned*)alloc((size_t)NN * 4);
    unsigned* offs     = (unsigned*)alloc((size_t)(NN + 1) * 4);
    unsigned* cursor   = (unsigned*)alloc((size_t)NN * 4);
    unsigned* chunkSum = (unsigned*)alloc((size_t)NCH * 4);
    unsigned* chunkOff = (unsigned*)alloc((size_t)NCH * 4);
    unsigned* posOf    = (unsigned*)alloc((size_t)EE * 4);
    unsigned* src_s    = (unsigned*)alloc((size_t)EE * 4);
    float2*   ae1s     = (float2*)alloc((size_t)EE * 8);
    float2*   ae2s     = (float2*)alloc((size_t)EE * 8);
    float2*   asrcv    = (float2*)alloc((size_t)NN * 8);
    float2*   adstv    = (float2*)alloc((size_t)NN * 8);
    __half2*  hp       = (__half2*)alloc((size_t)NN * 64 * 4);
    float*    mid      = (float*)alloc((size_t)NN * 64 * 4);
    float*    rn1      = (float*)alloc((size_t)NN * 4);
    float*    rn2      = (float*)alloc((size_t)NN * 4);
    float*    Wq1      = (float*)alloc(8192 * 4);
    float*    Wq2      = (float*)alloc(8192 * 4);
    float*    v1       = (float*)alloc(64 * 4);
    float*    v2       = (float*)alloc(64 * 4);
    unsigned* slots1   = (unsigned*)alloc(256 * 4);
    unsigned* slots2   = (unsigned*)alloc(256 * 4);

    dim3 B(256);
    k_init<<<391, B, 0, stream>>>(deg_src, deg_dst, slots1, slots2);
    k_deg<<<3125, B, 0, stream>>>(ei, deg_src, deg_dst);
    k_scan_chunksum<<<NCH, B, 0, stream>>>(deg_dst, chunkSum);
    k_scan_chunkoff<<<1, B, 0, stream>>>(chunkSum, chunkOff, offs);
    k_scan_final<<<NCH, B, 0, stream>>>(deg_dst, chunkOff, offs, cursor,
                                        deg_src, a1, a2, rn1, rn2);
    k_scatter<<<3125, B, 0, stream>>>(ei, cursor, posOf, src_s);
    k_weights<<<2, B, 0, stream>>>(W1, W2, We1, ae1, We2, ae2, Wq1, Wq2, v1, v2);
    k_aedge<<<3125, B, 0, stream>>>(eattr, v1, v2, posOf, ae1s, ae2s);
    // layer 1
    k_hproj<<<3125, B, 0, stream>>>(x, rn1, nullptr, Wq1, as1, ad1, hp, asrcv, adstv);
    k_aggregate<<<25000, B, 0, stream>>>(offs, src_s, ae1s, asrcv, adstv, hp, b1, mid, slots1);
    // layer 2 (quant+relu+rnorm fused into hproj staging)
    k_hproj<<<3125, B, 0, stream>>>(mid, rn2, slots1, Wq2, as2, ad2, hp, asrcv, adstv);
    k_aggregate<<<25000, B, 0, stream>>>(offs, src_s, ae2s, asrcv, adstv, hp, b2, out, slots2);
    k_quant_out<<<25000, B, 0, stream>>>(out, slots2);
}

// Round 7
// 825.109 us; speedup vs baseline: 1.0367x; 1.0367x over previous
//
#include <hip/hip_runtime.h>
#include <hip/hip_bf16.h>
#include <hip/hip_fp16.h>
#include <math.h>

#define NN 100000
#define EE 800000

static constexpr int SCAN_CH = 512;
static constexpr int NCH = (NN + SCAN_CH - 1) / SCAN_CH; // 196

__device__ __forceinline__ float leaky(float a) { return a >= 0.0f ? a : 0.2f * a; }
__device__ __forceinline__ float quantize(float v, float s) {
    float r = rintf(v / s);
    r = fminf(fmaxf(r, -128.0f), 127.0f);
    return r * s;
}

// ---------------- init: zero counters ----------------
__global__ void k_init(unsigned* deg_src, unsigned* deg_dst, unsigned* s1, unsigned* s2) {
    int i = blockIdx.x * 256 + threadIdx.x;
    if (i < NN) { deg_src[i] = 0; deg_dst[i] = 0; }
    if (i < 256) { s1[i] = 0; s2[i] = 0; }
}

// ---------------- degree count ----------------
__global__ void k_deg(const int* ei, unsigned* deg_src, unsigned* deg_dst) {
    int e = blockIdx.x * 256 + threadIdx.x;
    if (e < EE) {
        atomicAdd(&deg_src[ei[e]], 1u);
        atomicAdd(&deg_dst[ei[EE + e]], 1u);
    }
}

// ---------------- scan (3 kernels) ----------------
__global__ void k_scan_chunksum(const unsigned* deg_dst, unsigned* chunkSum) {
    __shared__ unsigned red[256];
    int b = blockIdx.x, t = threadIdx.x;
    int g0 = b * SCAN_CH + t;
    unsigned v = 0;
    if (g0 < NN) v += deg_dst[g0];
    if (g0 + 256 < NN && t + 256 < SCAN_CH) v += deg_dst[g0 + 256];
    red[t] = v; __syncthreads();
    for (int s = 128; s > 0; s >>= 1) { if (t < s) red[t] += red[t + s]; __syncthreads(); }
    if (t == 0) chunkSum[b] = red[0];
}

__global__ void k_scan_chunkoff(const unsigned* chunkSum, unsigned* chunkOff, unsigned* off) {
    __shared__ unsigned sc[256];
    int t = threadIdx.x;
    unsigned v = (t < NCH) ? chunkSum[t] : 0u;
    sc[t] = v; __syncthreads();
    for (int d = 1; d < 256; d <<= 1) {
        unsigned add = (t >= d) ? sc[t - d] : 0u; __syncthreads();
        sc[t] += add; __syncthreads();
    }
    if (t < NCH) chunkOff[t] = sc[t] - v;
    if (t == 255) off[NN] = sc[255];
}

// final scan + cursor init + degree-norm tables (fused)
__global__ void k_scan_final(const unsigned* deg_dst, const unsigned* chunkOff,
                             unsigned* off, unsigned* cursor,
                             const unsigned* deg_src, const float* a1p, const float* a2p,
                             float* rn1, float* rn2) {
    __shared__ unsigned sc[256];
    int b = blockIdx.x, t = threadIdx.x;
    int g0 = b * SCAN_CH + 2 * t;
    unsigned a = (g0 < NN) ? deg_dst[g0] : 0u;
    unsigned c = (g0 + 1 < NN) ? deg_dst[g0 + 1] : 0u;
    unsigned ps = a + c;
    sc[t] = ps; __syncthreads();
    for (int d = 1; d < 256; d <<= 1) {
        unsigned add = (t >= d) ? sc[t - d] : 0u; __syncthreads();
        sc[t] += add; __syncthreads();
    }
    unsigned base = chunkOff[b] + sc[t] - ps;
    float e1 = -a1p[0], e2 = -a2p[0];
    if (g0 < NN) {
        off[g0] = base; cursor[g0] = base;
        float d0 = (float)deg_src[g0] + 1.0f;
        rn1[g0] = powf(d0, e1); rn2[g0] = powf(d0, e2);
    }
    if (g0 + 1 < NN) {
        off[g0 + 1] = base + a; cursor[g0 + 1] = base + a;
        float d1 = (float)deg_src[g0 + 1] + 1.0f;
        rn1[g0 + 1] = powf(d1, e1); rn2[g0 + 1] = powf(d1, e2);
    }
}

// ---------------- scatter: sort edges by dst, ONE scattered 8B stream ----------------
__global__ void k_scatter(const int* ei, unsigned* cursor, uint2* sp) {
    int e = blockIdx.x * 256 + threadIdx.x;
    if (e < EE) {
        int d = ei[EE + e];
        unsigned pos = atomicAdd(&cursor[d], 1u);
        sp[pos] = make_uint2((unsigned)ei[e], (unsigned)e);   // {src, edge id}
    }
}

// ---------------- weight fake-quant + a_edge projection vectors ----------------
// block 0: layer 1, block 1: layer 2
__global__ void k_weights(const float* W1, const float* W2,
                          const float* We1, const float* ae1,
                          const float* We2, const float* ae2,
                          float* Wq1, float* Wq2, float* v1, float* v2) {
    __shared__ float red[256];
    int t = threadIdx.x;
    const float* W  = blockIdx.x ? W2 : W1;
    const float* We = blockIdx.x ? We2 : We1;
    const float* ae = blockIdx.x ? ae2 : ae1;
    float* Wq = blockIdx.x ? Wq2 : Wq1;
    float* v  = blockIdx.x ? v2 : v1;
    float m = 0.0f;
    for (int i = t; i < 8192; i += 256) m = fmaxf(m, fabsf(W[i]));
    red[t] = m; __syncthreads();
    for (int s = 128; s > 0; s >>= 1) { if (t < s) red[t] = fmaxf(red[t], red[t + s]); __syncthreads(); }
    float s1 = fmaxf(red[0], 1e-8f) / 127.0f;
    __syncthreads();
    for (int i = t; i < 8192; i += 256) Wq[i] = quantize(W[i], s1);
    if (t < 64) {
        int h = t >> 5, d = t & 31;
        float acc = 0.0f;
        for (int c = 0; c < 64; ++c) acc += We[(h * 64 + c) * 32 + d] * ae[h * 64 + c];
        v[t] = acc;
    }
}

// ---------------- a_edge for both layers, edge order (fully coalesced) ----------------
__global__ void k_aedge(const float* edge_attr, const float* v1, const float* v2,
                        float2* ae1e, float2* ae2e) {
    __shared__ float vs[128];
    int t = threadIdx.x;
    if (t < 64) vs[t] = v1[t];
    else if (t < 128) vs[t] = v2[t - 64];
    __syncthreads();
    int e = blockIdx.x * 256 + t;
    if (e >= EE) return;
    const float4* ea = (const float4*)(edge_attr + (size_t)e * 32);
    float a00 = 0, a01 = 0, a10 = 0, a11 = 0;
#pragma unroll
    for (int q = 0; q < 8; ++q) {
        float4 w = ea[q];
        float xs4[4] = {w.x, w.y, w.z, w.w};
#pragma unroll
        for (int j = 0; j < 4; ++j) {
            int d = q * 4 + j;
            a00 += xs4[j] * vs[d];
            a01 += xs4[j] * vs[32 + d];
            a10 += xs4[j] * vs[64 + d];
            a11 += xs4[j] * vs[96 + d];
        }
    }
    ae1e[e] = make_float2(a00, a01);
    ae2e[e] = make_float2(a10, a11);
}

// ---------------- h = f(in) @ Wq.T (+ a_src/a_dst dots), h stored fp16 ----------------
// slots==nullptr: f = rn-scale (layer 1).  slots!=nullptr: f = rn2*relu(quant(v,s1)) (layer 2).
__global__ void __launch_bounds__(256, 2)
k_hproj(const float* __restrict__ in, const float* __restrict__ rn,
        const unsigned* __restrict__ slots,
        const float* __restrict__ Wq,
        const float* __restrict__ att_s, const float* __restrict__ att_d,
        __half2* __restrict__ hp, float2* __restrict__ asrcv,
        float2* __restrict__ adstv) {
    __shared__ float xs[32][64];   // 8 KB
    __shared__ unsigned redu[256];
    int t = threadIdx.x;
    float qs = 0.0f;
    if (slots) {   // fused absmax-slot reduction -> s1
        redu[t] = slots[t]; __syncthreads();
        for (int s = 128; s > 0; s >>= 1) {
            if (t < s) redu[t] = (redu[t] > redu[t + s]) ? redu[t] : redu[t + s];
            __syncthreads();
        }
        qs = fmaxf(__uint_as_float(redu[0]), 1e-8f) / 127.0f;
        __syncthreads();
    }
    int node0 = blockIdx.x * 32;
    for (int i = t; i < 512; i += 256) {
        int n = i >> 4, c4 = i & 15;
        int node = node0 + n;
        float4 v = make_float4(0.f, 0.f, 0.f, 0.f);
        if (node < NN) {
            v = ((const float4*)(in + (size_t)node * 64))[c4];
            float r = rn[node];
            if (slots) {
                v.x = fmaxf(quantize(v.x, qs), 0.f) * r;
                v.y = fmaxf(quantize(v.y, qs), 0.f) * r;
                v.z = fmaxf(quantize(v.z, qs), 0.f) * r;
                v.w = fmaxf(quantize(v.w, qs), 0.f) * r;
            } else {
                v.x *= r; v.y *= r; v.z *= r; v.w *= r;
            }
        }
        ((float4*)xs[n])[c4] = v;
    }
    int w = t >> 6, l = t & 63;
    float4 w0[16], w1[16];
    const float4* wp0 = (const float4*)(Wq + (size_t)l * 64);
    const float4* wp1 = (const float4*)(Wq + (size_t)(64 + l) * 64);
#pragma unroll
    for (int q = 0; q < 16; ++q) { w0[q] = wp0[q]; w1[q] = wp1[q]; }
    float as0 = att_s[l], as1 = att_s[64 + l];
    float ad0 = att_d[l], ad1 = att_d[64 + l];
    __syncthreads();
    for (int nn = 0; nn < 8; ++nn) {
        int node = node0 + w * 8 + nn;
        if (node >= NN) break;
        const float4* xr = (const float4*)xs[w * 8 + nn];
        float a0 = 0.0f, a1 = 0.0f;
#pragma unroll
        for (int q = 0; q < 16; ++q) {
            float4 xv = xr[q];             // uniform address -> LDS broadcast
            a0 += xv.x * w0[q].x + xv.y * w0[q].y + xv.z * w0[q].z + xv.w * w0[q].w;
            a1 += xv.x * w1[q].x + xv.y * w1[q].y + xv.z * w1[q].z + xv.w * w1[q].w;
        }
        hp[(size_t)node * 64 + l] = __floats2half2_rn(a0, a1);
        float ps0 = a0 * as0, ps1 = a1 * as1, pd0 = a0 * ad0, pd1 = a1 * ad1;
#pragma unroll
        for (int m = 32; m > 0; m >>= 1) {
            ps0 += __shfl_xor(ps0, m, 64);
            ps1 += __shfl_xor(ps1, m, 64);
            pd0 += __shfl_xor(pd0, m, 64);
            pd1 += __shfl_xor(pd1, m, 64);
        }
        if (l == 0) {
            asrcv[node] = make_float2(ps0, ps1);
            adstv[node] = make_float2(pd0, pd1);
        }
    }
}

// ---------------- fused softmax+aggregate: wave per dst node ----------------
// Phase 1 (lane-parallel): lanes l<deg read sp (coalesced), gather aee[edge] + asrcv[src],
//                          compute p = exp(leaky(.)) once per edge.
// Phase 2 (broadcast): readlane (src, p); 8 independent fp16 hp-row gathers per group.
__global__ void k_aggregate(const unsigned* __restrict__ off, const uint2* __restrict__ sp,
                            const float2* __restrict__ aee,
                            const float2* __restrict__ asrcv, const float2* __restrict__ adstv,
                            const __half2* __restrict__ hp, const float* __restrict__ bias,
                            float* __restrict__ outp, unsigned* __restrict__ amax_slots) {
    int t = threadIdx.x;
    int l = t & 63;
    int node = blockIdx.x * 4 + (t >> 6);
    if (node >= NN) return;
    unsigned s0 = off[node], e0 = off[node + 1];
    float2 adv = adstv[node];
    float bl = bias[l];
    float acc0 = 0.f, acc1 = 0.f, psum0 = 0.f, psum1 = 0.f;
    for (unsigned base = s0; base < e0; base += 64) {
        int cnt = (int)min(64u, e0 - base);
        float p0 = 0.f, p1 = 0.f;
        unsigned s = 0u;
        if (l < cnt) {
            uint2 se = sp[base + l];             // coalesced {src, edge}
            s = se.x;
            float2 ev = aee[se.y];               // parallel 8B gather (L2/L3-resident 6.4MB)
            float2 av = asrcv[s];                // parallel 8B gather (800KB)
            p0 = __expf(leaky(av.x + adv.x + ev.x));
            p1 = __expf(leaky(av.y + adv.y + ev.y));
        }
        psum0 += p0; psum1 += p1;
        int su = (int)s;
        unsigned pu0 = __float_as_uint(p0), pu1 = __float_as_uint(p1);
        for (int j = 0; j < cnt; j += 8) {
            float2 f[8]; float q0[8], q1[8];
#pragma unroll
            for (int k = 0; k < 8; ++k) {
                unsigned sk = (unsigned)__builtin_amdgcn_readlane(su, j + k);
                __half2 h = hp[(size_t)sk * 64 + l];
                f[k] = __half22float2(h);
                q0[k] = __uint_as_float((unsigned)__builtin_amdgcn_readlane((int)pu0, j + k));
                q1[k] = __uint_as_float((unsigned)__builtin_amdgcn_readlane((int)pu1, j + k));
            }
#pragma unroll
            for (int k = 0; k < 8; ++k) {
                acc0 = fmaf(q0[k], f[k].x, acc0);
                acc1 = fmaf(q1[k], f[k].y, acc1);
            }
        }
    }
#pragma unroll
    for (int m = 32; m > 0; m >>= 1) {
        psum0 += __shfl_xor(psum0, m, 64);
        psum1 += __shfl_xor(psum1, m, 64);
    }
    float o = 0.5f * (acc0 / (psum0 + 1e-16f) + acc1 / (psum1 + 1e-16f)) + bl;
    outp[(size_t)node * 64 + l] = o;
    float v = fabsf(o);
#pragma unroll
    for (int m = 32; m > 0; m >>= 1) v = fmaxf(v, __shfl_xor(v, m, 64));
    if (l == 0) atomicMax(&amax_slots[node & 255], __float_as_uint(v));
}

// ---------------- final output fake-quant in place (fused slot reduce) ----------------
__global__ void k_quant_out(float* buf, const unsigned* slots) {
    __shared__ unsigned red[256];
    int t = threadIdx.x;
    red[t] = slots[t]; __syncthreads();
    for (int s = 128; s > 0; s >>= 1) {
        if (t < s) red[t] = (red[t] > red[t + s]) ? red[t] : red[t + s];
        __syncthreads();
    }
    float s2 = fmaxf(__uint_as_float(red[0]), 1e-8f) / 127.0f;
    int i = blockIdx.x * 256 + t;
    if (i < NN * 64) buf[i] = quantize(buf[i], s2);
}

extern "C" void kernel_launch(void* const* d_in, const int* in_sizes, int n_in,
                              void* d_out, int out_size, void* d_ws, size_t ws_size,
                              hipStream_t stream) {
    const float* x     = (const float*)d_in[0];
    const int*   ei    = (const int*)d_in[1];
    const float* eattr = (const float*)d_in[2];
    const float* a1    = (const float*)d_in[3];
    const float* W1    = (const float*)d_in[4];
    const float* We1   = (const float*)d_in[5];
    const float* as1   = (const float*)d_in[6];
    const float* ad1   = (const float*)d_in[7];
    const float* ae1   = (const float*)d_in[8];
    const float* b1    = (const float*)d_in[9];
    const float* a2    = (const float*)d_in[10];
    const float* W2    = (const float*)d_in[11];
    const float* We2   = (const float*)d_in[12];
    const float* as2   = (const float*)d_in[13];
    const float* ad2   = (const float*)d_in[14];
    const float* ae2   = (const float*)d_in[15];
    const float* b2    = (const float*)d_in[16];
    float* out = (float*)d_out;

    char* w = (char*)d_ws;
    size_t o = 0;
    auto alloc = [&](size_t bytes) -> char* {
        char* p = w + o;
        o += (bytes + 255) & ~(size_t)255;
        return p;
    };
    unsigned* deg_src  = (unsigned*)alloc((size_t)NN * 4);
    unsigned* deg_dst  = (unsigned*)alloc((size_t)NN * 4);
    unsigned* offs     = (unsigned*)alloc((size_t)(NN + 1) * 4);
    unsigned* cursor   = (unsigned*)alloc((size_t)NN * 4);
    unsigned* chunkSum = (unsigned*)alloc((size_t)NCH * 4);
    unsigned* chunkOff = (unsigned*)alloc((size_t)NCH * 4);
    uint2*    sp       = (uint2*)alloc((size_t)EE * 8);
    float2*   ae1e     = (float2*)alloc((size_t)EE * 8);
    float2*   ae2e     = (float2*)alloc((size_t)EE * 8);
    float2*   asrcv    = (float2*)alloc((size_t)NN * 8);
    float2*   adstv    = (float2*)alloc((size_t)NN * 8);
    __half2*  hp       = (__half2*)alloc((size_t)NN * 64 * 4);
    float*    mid      = (float*)alloc((size_t)NN * 64 * 4);
    float*    rn1      = (float*)alloc((size_t)NN * 4);
    float*    rn2      = (float*)alloc((size_t)NN * 4);
    float*    Wq1      = (float*)alloc(8192 * 4);
    float*    Wq2      = (float*)alloc(8192 * 4);
    float*    v1       = (float*)alloc(64 * 4);
    float*    v2       = (float*)alloc(64 * 4);
    unsigned* slots1   = (unsigned*)alloc(256 * 4);
    unsigned* slots2   = (unsigned*)alloc(256 * 4);

    dim3 B(256);
    k_init<<<391, B, 0, stream>>>(deg_src, deg_dst, slots1, slots2);
    k_deg<<<3125, B, 0, stream>>>(ei, deg_src, deg_dst);
    k_scan_chunksum<<<NCH, B, 0, stream>>>(deg_dst, chunkSum);
    k_scan_chunkoff<<<1, B, 0, stream>>>(chunkSum, chunkOff, offs);
    k_scan_final<<<NCH, B, 0, stream>>>(deg_dst, chunkOff, offs, cursor,
                                        deg_src, a1, a2, rn1, rn2);
    k_scatter<<<3125, B, 0, stream>>>(ei, cursor, sp);
    k_weights<<<2, B, 0, stream>>>(W1, W2, We1, ae1, We2, ae2, Wq1, Wq2, v1, v2);
    k_aedge<<<3125, B, 0, stream>>>(eattr, v1, v2, ae1e, ae2e);
    // layer 1
    k_hproj<<<3125, B, 0, stream>>>(x, rn1, nullptr, Wq1, as1, ad1, hp, asrcv, adstv);
    k_aggregate<<<25000, B, 0, stream>>>(offs, sp, ae1e, asrcv, adstv, hp, b1, mid, slots1);
    // layer 2 (quant+relu+rnorm fused into hproj staging)
    k_hproj<<<3125, B, 0, stream>>>(mid, rn2, slots1, Wq2, as2, ad2, hp, asrcv, adstv);
    k_aggregate<<<25000, B, 0, stream>>>(offs, sp, ae2e, asrcv, adstv, hp, b2, out, slots2);
    k_quant_out<<<25000, B, 0, stream>>>(out, slots2);
}

// Round 8
// 670.177 us; speedup vs baseline: 1.2764x; 1.2312x over previous
//
#include <hip/hip_runtime.h>
#include <hip/hip_bf16.h>
#include <hip/hip_fp16.h>
#include <math.h>

#define NN 100000
#define EE 800000

static constexpr int SCAN_CH = 512;
static constexpr int NCH = (NN + SCAN_CH - 1) / SCAN_CH; // 196

__device__ __forceinline__ float leaky(float a) { return a >= 0.0f ? a : 0.2f * a; }
__device__ __forceinline__ float quantize(float v, float s) {
    float r = rintf(v / s);
    r = fminf(fmaxf(r, -128.0f), 127.0f);
    return r * s;
}

// ---------------- init: zero degree counters ----------------
__global__ void k_init(unsigned* deg_src, unsigned* deg_dst) {
    int i = blockIdx.x * 256 + threadIdx.x;
    if (i < NN) { deg_src[i] = 0; deg_dst[i] = 0; }
}

// ---------------- degree count ----------------
__global__ void k_deg(const int* ei, unsigned* deg_src, unsigned* deg_dst) {
    int e = blockIdx.x * 256 + threadIdx.x;
    if (e < EE) {
        atomicAdd(&deg_src[ei[e]], 1u);
        atomicAdd(&deg_dst[ei[EE + e]], 1u);
    }
}

// ---------------- scan (3 kernels) ----------------
__global__ void k_scan_chunksum(const unsigned* deg_dst, unsigned* chunkSum) {
    __shared__ unsigned red[256];
    int b = blockIdx.x, t = threadIdx.x;
    int g0 = b * SCAN_CH + t;
    unsigned v = 0;
    if (g0 < NN) v += deg_dst[g0];
    if (g0 + 256 < NN && t + 256 < SCAN_CH) v += deg_dst[g0 + 256];
    red[t] = v; __syncthreads();
    for (int s = 128; s > 0; s >>= 1) { if (t < s) red[t] += red[t + s]; __syncthreads(); }
    if (t == 0) chunkSum[b] = red[0];
}

__global__ void k_scan_chunkoff(const unsigned* chunkSum, unsigned* chunkOff, unsigned* off) {
    __shared__ unsigned sc[256];
    int t = threadIdx.x;
    unsigned v = (t < NCH) ? chunkSum[t] : 0u;
    sc[t] = v; __syncthreads();
    for (int d = 1; d < 256; d <<= 1) {
        unsigned add = (t >= d) ? sc[t - d] : 0u; __syncthreads();
        sc[t] += add; __syncthreads();
    }
    if (t < NCH) chunkOff[t] = sc[t] - v;
    if (t == 255) off[NN] = sc[255];
}

// final scan + cursor init + degree-norm tables (fused)
__global__ void k_scan_final(const unsigned* deg_dst, const unsigned* chunkOff,
                             unsigned* off, unsigned* cursor,
                             const unsigned* deg_src, const float* a1p, const float* a2p,
                             float* rn1, float* rn2) {
    __shared__ unsigned sc[256];
    int b = blockIdx.x, t = threadIdx.x;
    int g0 = b * SCAN_CH + 2 * t;
    unsigned a = (g0 < NN) ? deg_dst[g0] : 0u;
    unsigned c = (g0 + 1 < NN) ? deg_dst[g0 + 1] : 0u;
    unsigned ps = a + c;
    sc[t] = ps; __syncthreads();
    for (int d = 1; d < 256; d <<= 1) {
        unsigned add = (t >= d) ? sc[t - d] : 0u; __syncthreads();
        sc[t] += add; __syncthreads();
    }
    unsigned base = chunkOff[b] + sc[t] - ps;
    float e1 = -a1p[0], e2 = -a2p[0];
    if (g0 < NN) {
        off[g0] = base; cursor[g0] = base;
        float d0 = (float)deg_src[g0] + 1.0f;
        rn1[g0] = powf(d0, e1); rn2[g0] = powf(d0, e2);
    }
    if (g0 + 1 < NN) {
        off[g0 + 1] = base + a; cursor[g0 + 1] = base + a;
        float d1 = (float)deg_src[g0 + 1] + 1.0f;
        rn1[g0 + 1] = powf(d1, e1); rn2[g0 + 1] = powf(d1, e2);
    }
}

// ---------------- scatter: sort edges by dst, ONE scattered 8B stream ----------------
__global__ void k_scatter(const int* ei, unsigned* cursor, uint2* sp) {
    int e = blockIdx.x * 256 + threadIdx.x;
    if (e < EE) {
        int d = ei[EE + e];
        unsigned pos = atomicAdd(&cursor[d], 1u);
        sp[pos] = make_uint2((unsigned)ei[e], (unsigned)e);   // {src, edge id}
    }
}

// ---------------- weight fake-quant + a_edge projection vectors ----------------
// block 0: layer 1, block 1: layer 2
__global__ void k_weights(const float* W1, const float* W2,
                          const float* We1, const float* ae1,
                          const float* We2, const float* ae2,
                          float* Wq1, float* Wq2, float* v1, float* v2) {
    __shared__ float red[256];
    int t = threadIdx.x;
    const float* W  = blockIdx.x ? W2 : W1;
    const float* We = blockIdx.x ? We2 : We1;
    const float* ae = blockIdx.x ? ae2 : ae1;
    float* Wq = blockIdx.x ? Wq2 : Wq1;
    float* v  = blockIdx.x ? v2 : v1;
    float m = 0.0f;
    for (int i = t; i < 8192; i += 256) m = fmaxf(m, fabsf(W[i]));
    red[t] = m; __syncthreads();
    for (int s = 128; s > 0; s >>= 1) { if (t < s) red[t] = fmaxf(red[t], red[t + s]); __syncthreads(); }
    float s1 = fmaxf(red[0], 1e-8f) / 127.0f;
    __syncthreads();
    for (int i = t; i < 8192; i += 256) Wq[i] = quantize(W[i], s1);
    if (t < 64) {
        int h = t >> 5, d = t & 31;
        float acc = 0.0f;
        for (int c = 0; c < 64; ++c) acc += We[(h * 64 + c) * 32 + d] * ae[h * 64 + c];
        v[t] = acc;
    }
}

// ---------------- a_edge for both layers, edge order (fully coalesced) ----------------
__global__ void k_aedge(const float* edge_attr, const float* v1, const float* v2,
                        float2* ae1e, float2* ae2e) {
    __shared__ float vs[128];
    int t = threadIdx.x;
    if (t < 64) vs[t] = v1[t];
    else if (t < 128) vs[t] = v2[t - 64];
    __syncthreads();
    int e = blockIdx.x * 256 + t;
    if (e >= EE) return;
    const float4* ea = (const float4*)(edge_attr + (size_t)e * 32);
    float a00 = 0, a01 = 0, a10 = 0, a11 = 0;
#pragma unroll
    for (int q = 0; q < 8; ++q) {
        float4 w = ea[q];
        float xs4[4] = {w.x, w.y, w.z, w.w};
#pragma unroll
        for (int j = 0; j < 4; ++j) {
            int d = q * 4 + j;
            a00 += xs4[j] * vs[d];
            a01 += xs4[j] * vs[32 + d];
            a10 += xs4[j] * vs[64 + d];
            a11 += xs4[j] * vs[96 + d];
        }
    }
    ae1e[e] = make_float2(a00, a01);
    ae2e[e] = make_float2(a10, a11);
}

// ---------------- h = f(in) @ Wq.T (+ a_src/a_dst dots), h stored fp16 ----------------
// slots==nullptr: f = rn-scale (layer 1).  slots!=nullptr: f = rn2*relu(quant(v,s1)) (layer 2).
__global__ void __launch_bounds__(256, 2)
k_hproj(const float* __restrict__ in, const float* __restrict__ rn,
        const unsigned* __restrict__ slots,
        const float* __restrict__ Wq,
        const float* __restrict__ att_s, const float* __restrict__ att_d,
        __half2* __restrict__ hp, float2* __restrict__ asrcv,
        float2* __restrict__ adstv) {
    __shared__ float xs[32][64];   // 8 KB
    __shared__ unsigned redu[256];
    int t = threadIdx.x;
    float qs = 0.0f;
    if (slots) {   // fused absmax-slot reduction -> s1
        redu[t] = slots[t]; __syncthreads();
        for (int s = 128; s > 0; s >>= 1) {
            if (t < s) redu[t] = (redu[t] > redu[t + s]) ? redu[t] : redu[t + s];
            __syncthreads();
        }
        qs = fmaxf(__uint_as_float(redu[0]), 1e-8f) / 127.0f;
        __syncthreads();
    }
    int node0 = blockIdx.x * 32;
    for (int i = t; i < 512; i += 256) {
        int n = i >> 4, c4 = i & 15;
        int node = node0 + n;
        float4 v = make_float4(0.f, 0.f, 0.f, 0.f);
        if (node < NN) {
            v = ((const float4*)(in + (size_t)node * 64))[c4];
            float r = rn[node];
            if (slots) {
                v.x = fmaxf(quantize(v.x, qs), 0.f) * r;
                v.y = fmaxf(quantize(v.y, qs), 0.f) * r;
                v.z = fmaxf(quantize(v.z, qs), 0.f) * r;
                v.w = fmaxf(quantize(v.w, qs), 0.f) * r;
            } else {
                v.x *= r; v.y *= r; v.z *= r; v.w *= r;
            }
        }
        ((float4*)xs[n])[c4] = v;
    }
    int w = t >> 6, l = t & 63;
    float4 w0[16], w1[16];
    const float4* wp0 = (const float4*)(Wq + (size_t)l * 64);
    const float4* wp1 = (const float4*)(Wq + (size_t)(64 + l) * 64);
#pragma unroll
    for (int q = 0; q < 16; ++q) { w0[q] = wp0[q]; w1[q] = wp1[q]; }
    float as0 = att_s[l], as1 = att_s[64 + l];
    float ad0 = att_d[l], ad1 = att_d[64 + l];
    __syncthreads();
    for (int nn = 0; nn < 8; ++nn) {
        int node = node0 + w * 8 + nn;
        if (node >= NN) break;
        const float4* xr = (const float4*)xs[w * 8 + nn];
        float a0 = 0.0f, a1 = 0.0f;
#pragma unroll
        for (int q = 0; q < 16; ++q) {
            float4 xv = xr[q];             // uniform address -> LDS broadcast
            a0 += xv.x * w0[q].x + xv.y * w0[q].y + xv.z * w0[q].z + xv.w * w0[q].w;
            a1 += xv.x * w1[q].x + xv.y * w1[q].y + xv.z * w1[q].z + xv.w * w1[q].w;
        }
        hp[(size_t)node * 64 + l] = __floats2half2_rn(a0, a1);
        float ps0 = a0 * as0, ps1 = a1 * as1, pd0 = a0 * ad0, pd1 = a1 * ad1;
#pragma unroll
        for (int m = 32; m > 0; m >>= 1) {
            ps0 += __shfl_xor(ps0, m, 64);
            ps1 += __shfl_xor(ps1, m, 64);
            pd0 += __shfl_xor(pd0, m, 64);
            pd1 += __shfl_xor(pd1, m, 64);
        }
        if (l == 0) {
            asrcv[node] = make_float2(ps0, ps1);
            adstv[node] = make_float2(pd0, pd1);
        }
    }
}

// ---------------- fused softmax+aggregate: wave per dst node ----------------
// Phase 1 (lane-parallel): lanes l<deg read sp (coalesced), gather aee[edge] + asrcv[src],
//                          compute p = exp(leaky(.)) once per edge.
// Phase 2 (broadcast): readlane (src, p); 8 independent fp16 hp-row gathers per group.
// Per-node absmax written as a PLAIN STORE (no hot atomics).
__global__ void k_aggregate(const unsigned* __restrict__ off, const uint2* __restrict__ sp,
                            const float2* __restrict__ aee,
                            const float2* __restrict__ asrcv, const float2* __restrict__ adstv,
                            const __half2* __restrict__ hp, const float* __restrict__ bias,
                            float* __restrict__ outp, float* __restrict__ amax_node) {
    int t = threadIdx.x;
    int l = t & 63;
    int node = blockIdx.x * 4 + (t >> 6);
    if (node >= NN) return;
    unsigned s0 = off[node], e0 = off[node + 1];
    float2 adv = adstv[node];
    float bl = bias[l];
    float acc0 = 0.f, acc1 = 0.f, psum0 = 0.f, psum1 = 0.f;
    for (unsigned base = s0; base < e0; base += 64) {
        int cnt = (int)min(64u, e0 - base);
        float p0 = 0.f, p1 = 0.f;
        unsigned s = 0u;
        if (l < cnt) {
            uint2 se = sp[base + l];             // coalesced {src, edge}
            s = se.x;
            float2 ev = aee[se.y];               // parallel 8B gather (L2/L3-resident 6.4MB)
            float2 av = asrcv[s];                // parallel 8B gather (800KB)
            p0 = __expf(leaky(av.x + adv.x + ev.x));
            p1 = __expf(leaky(av.y + adv.y + ev.y));
        }
        psum0 += p0; psum1 += p1;
        int su = (int)s;
        unsigned pu0 = __float_as_uint(p0), pu1 = __float_as_uint(p1);
        for (int j = 0; j < cnt; j += 8) {
            float2 f[8]; float q0[8], q1[8];
#pragma unroll
            for (int k = 0; k < 8; ++k) {
                unsigned sk = (unsigned)__builtin_amdgcn_readlane(su, j + k);
                __half2 h = hp[(size_t)sk * 64 + l];
                f[k] = __half22float2(h);
                q0[k] = __uint_as_float((unsigned)__builtin_amdgcn_readlane((int)pu0, j + k));
                q1[k] = __uint_as_float((unsigned)__builtin_amdgcn_readlane((int)pu1, j + k));
            }
#pragma unroll
            for (int k = 0; k < 8; ++k) {
                acc0 = fmaf(q0[k], f[k].x, acc0);
                acc1 = fmaf(q1[k], f[k].y, acc1);
            }
        }
    }
#pragma unroll
    for (int m = 32; m > 0; m >>= 1) {
        psum0 += __shfl_xor(psum0, m, 64);
        psum1 += __shfl_xor(psum1, m, 64);
    }
    float o = 0.5f * (acc0 / (psum0 + 1e-16f) + acc1 / (psum1 + 1e-16f)) + bl;
    outp[(size_t)node * 64 + l] = o;
    float v = fabsf(o);
#pragma unroll
    for (int m = 32; m > 0; m >>= 1) v = fmaxf(v, __shfl_xor(v, m, 64));
    if (l == 0) amax_node[node] = v;          // plain store, zero contention
}

// ---------------- per-node absmax -> 256 partial slots (no atomics) ----------------
__global__ void k_amax_partial(const float* __restrict__ amax_node, unsigned* __restrict__ slots) {
    __shared__ float red[256];
    int t = threadIdx.x;
    float m = 0.0f;
    for (int i = blockIdx.x * 256 + t; i < NN; i += 256 * 256)
        m = fmaxf(m, amax_node[i]);
    red[t] = m; __syncthreads();
    for (int s = 128; s > 0; s >>= 1) {
        if (t < s) red[t] = fmaxf(red[t], red[t + s]);
        __syncthreads();
    }
    if (t == 0) slots[blockIdx.x] = __float_as_uint(red[0]);  // own slot, no contention
}

// ---------------- final output fake-quant in place (fused slot reduce) ----------------
__global__ void k_quant_out(float* buf, const unsigned* slots) {
    __shared__ unsigned red[256];
    int t = threadIdx.x;
    red[t] = slots[t]; __syncthreads();
    for (int s = 128; s > 0; s >>= 1) {
        if (t < s) red[t] = (red[t] > red[t + s]) ? red[t] : red[t + s];
        __syncthreads();
    }
    float s2 = fmaxf(__uint_as_float(red[0]), 1e-8f) / 127.0f;
    int i = blockIdx.x * 256 + t;
    if (i < NN * 64) buf[i] = quantize(buf[i], s2);
}

extern "C" void kernel_launch(void* const* d_in, const int* in_sizes, int n_in,
                              void* d_out, int out_size, void* d_ws, size_t ws_size,
                              hipStream_t stream) {
    const float* x     = (const float*)d_in[0];
    const int*   ei    = (const int*)d_in[1];
    const float* eattr = (const float*)d_in[2];
    const float* a1    = (const float*)d_in[3];
    const float* W1    = (const float*)d_in[4];
    const float* We1   = (const float*)d_in[5];
    const float* as1   = (const float*)d_in[6];
    const float* ad1   = (const float*)d_in[7];
    const float* ae1   = (const float*)d_in[8];
    const float* b1    = (const float*)d_in[9];
    const float* a2    = (const float*)d_in[10];
    const float* W2    = (const float*)d_in[11];
    const float* We2   = (const float*)d_in[12];
    const float* as2   = (const float*)d_in[13];
    const float* ad2   = (const float*)d_in[14];
    const float* ae2   = (const float*)d_in[15];
    const float* b2    = (const float*)d_in[16];
    float* out = (float*)d_out;

    char* w = (char*)d_ws;
    size_t o = 0;
    auto alloc = [&](size_t bytes) -> char* {
        char* p = w + o;
        o += (bytes + 255) & ~(size_t)255;
        return p;
    };
    unsigned* deg_src  = (unsigned*)alloc((size_t)NN * 4);
    unsigned* deg_dst  = (unsigned*)alloc((size_t)NN * 4);
    unsigned* offs     = (unsigned*)alloc((size_t)(NN + 1) * 4);
    unsigned* cursor   = (unsigned*)alloc((size_t)NN * 4);
    unsigned* chunkSum = (unsigned*)alloc((size_t)NCH * 4);
    unsigned* chunkOff = (unsigned*)alloc((size_t)NCH * 4);
    uint2*    sp       = (uint2*)alloc((size_t)EE * 8);
    float2*   ae1e     = (float2*)alloc((size_t)EE * 8);
    float2*   ae2e     = (float2*)alloc((size_t)EE * 8);
    float2*   asrcv    = (float2*)alloc((size_t)NN * 8);
    float2*   adstv    = (float2*)alloc((size_t)NN * 8);
    __half2*  hp       = (__half2*)alloc((size_t)NN * 64 * 4);
    float*    mid      = (float*)alloc((size_t)NN * 64 * 4);
    float*    rn1      = (float*)alloc((size_t)NN * 4);
    float*    rn2      = (float*)alloc((size_t)NN * 4);
    float*    amaxn    = (float*)alloc((size_t)NN * 4);
    float*    Wq1      = (float*)alloc(8192 * 4);
    float*    Wq2      = (float*)alloc(8192 * 4);
    float*    v1       = (float*)alloc(64 * 4);
    float*    v2       = (float*)alloc(64 * 4);
    unsigned* slots1   = (unsigned*)alloc(256 * 4);
    unsigned* slots2   = (unsigned*)alloc(256 * 4);

    dim3 B(256);
    k_init<<<391, B, 0, stream>>>(deg_src, deg_dst);
    k_deg<<<3125, B, 0, stream>>>(ei, deg_src, deg_dst);
    k_scan_chunksum<<<NCH, B, 0, stream>>>(deg_dst, chunkSum);
    k_scan_chunkoff<<<1, B, 0, stream>>>(chunkSum, chunkOff, offs);
    k_scan_final<<<NCH, B, 0, stream>>>(deg_dst, chunkOff, offs, cursor,
                                        deg_src, a1, a2, rn1, rn2);
    k_scatter<<<3125, B, 0, stream>>>(ei, cursor, sp);
    k_weights<<<2, B, 0, stream>>>(W1, W2, We1, ae1, We2, ae2, Wq1, Wq2, v1, v2);
    k_aedge<<<3125, B, 0, stream>>>(eattr, v1, v2, ae1e, ae2e);
    // layer 1
    k_hproj<<<3125, B, 0, stream>>>(x, rn1, nullptr, Wq1, as1, ad1, hp, asrcv, adstv);
    k_aggregate<<<25000, B, 0, stream>>>(offs, sp, ae1e, asrcv, adstv, hp, b1, mid, amaxn);
    k_amax_partial<<<256, B, 0, stream>>>(amaxn, slots1);
    // layer 2 (quant+relu+rnorm fused into hproj staging)
    k_hproj<<<3125, B, 0, stream>>>(mid, rn2, slots1, Wq2, as2, ad2, hp, asrcv, adstv);
    k_aggregate<<<25000, B, 0, stream>>>(offs, sp, ae2e, asrcv, adstv, hp, b2, out, amaxn);
    k_amax_partial<<<256, B, 0, stream>>>(amaxn, slots2);
    k_quant_out<<<25000, B, 0, stream>>>(out, slots2);
}

// Round 10
// 643.261 us; speedup vs baseline: 1.3298x; 1.0418x over previous
//
#include <hip/hip_runtime.h>
#include <hip/hip_bf16.h>
#include <hip/hip_fp16.h>
#include <math.h>

#define NN 100000
#define EE 800000

static constexpr int SCAN_CH = 512;
static constexpr int NCH = (NN + SCAN_CH - 1) / SCAN_CH; // 196

__device__ __forceinline__ float leaky(float a) { return a >= 0.0f ? a : 0.2f * a; }
__device__ __forceinline__ float quantize(float v, float s) {
    float r = rintf(v / s);
    r = fminf(fmaxf(r, -128.0f), 127.0f);
    return r * s;
}

// ---------------- init: zero degree counters ----------------
__global__ void k_init(unsigned* deg_src, unsigned* deg_dst) {
    int i = blockIdx.x * 256 + threadIdx.x;
    if (i < NN) { deg_src[i] = 0; deg_dst[i] = 0; }
}

// ---------------- degree count ----------------
__global__ void k_deg(const int* ei, unsigned* deg_src, unsigned* deg_dst) {
    int e = blockIdx.x * 256 + threadIdx.x;
    if (e < EE) {
        atomicAdd(&deg_src[ei[e]], 1u);
        atomicAdd(&deg_dst[ei[EE + e]], 1u);
    }
}

// ---------------- scan (3 kernels) ----------------
__global__ void k_scan_chunksum(const unsigned* deg_dst, unsigned* chunkSum) {
    __shared__ unsigned red[256];
    int b = blockIdx.x, t = threadIdx.x;
    int g0 = b * SCAN_CH + t;
    unsigned v = 0;
    if (g0 < NN) v += deg_dst[g0];
    if (g0 + 256 < NN && t + 256 < SCAN_CH) v += deg_dst[g0 + 256];
    red[t] = v; __syncthreads();
    for (int s = 128; s > 0; s >>= 1) { if (t < s) red[t] += red[t + s]; __syncthreads(); }
    if (t == 0) chunkSum[b] = red[0];
}

__global__ void k_scan_chunkoff(const unsigned* chunkSum, unsigned* chunkOff, unsigned* off) {
    __shared__ unsigned sc[256];
    int t = threadIdx.x;
    unsigned v = (t < NCH) ? chunkSum[t] : 0u;
    sc[t] = v; __syncthreads();
    for (int d = 1; d < 256; d <<= 1) {
        unsigned add = (t >= d) ? sc[t - d] : 0u; __syncthreads();
        sc[t] += add; __syncthreads();
    }
    if (t < NCH) chunkOff[t] = sc[t] - v;
    if (t == 255) off[NN] = sc[255];
}

// final scan + cursor init + degree-norm tables (fused)
__global__ void k_scan_final(const unsigned* deg_dst, const unsigned* chunkOff,
                             unsigned* off, unsigned* cursor,
                             const unsigned* deg_src, const float* a1p, const float* a2p,
                             float* rn1, float* rn2) {
    __shared__ unsigned sc[256];
    int b = blockIdx.x, t = threadIdx.x;
    int g0 = b * SCAN_CH + 2 * t;
    unsigned a = (g0 < NN) ? deg_dst[g0] : 0u;
    unsigned c = (g0 + 1 < NN) ? deg_dst[g0 + 1] : 0u;
    unsigned ps = a + c;
    sc[t] = ps; __syncthreads();
    for (int d = 1; d < 256; d <<= 1) {
        unsigned add = (t >= d) ? sc[t - d] : 0u; __syncthreads();
        sc[t] += add; __syncthreads();
    }
    unsigned base = chunkOff[b] + sc[t] - ps;
    float e1 = -a1p[0], e2 = -a2p[0];
    if (g0 < NN) {
        off[g0] = base; cursor[g0] = base;
        float d0 = (float)deg_src[g0] + 1.0f;
        rn1[g0] = powf(d0, e1); rn2[g0] = powf(d0, e2);
    }
    if (g0 + 1 < NN) {
        off[g0 + 1] = base + a; cursor[g0 + 1] = base + a;
        float d1 = (float)deg_src[g0 + 1] + 1.0f;
        rn1[g0 + 1] = powf(d1, e1); rn2[g0 + 1] = powf(d1, e2);
    }
}

// ---------------- scatter: sort edges by dst, ONE scattered 8B stream ----------------
__global__ void k_scatter(const int* ei, unsigned* cursor, uint2* sp) {
    int e = blockIdx.x * 256 + threadIdx.x;
    if (e < EE) {
        int d = ei[EE + e];
        unsigned pos = atomicAdd(&cursor[d], 1u);
        sp[pos] = make_uint2((unsigned)ei[e], (unsigned)e);   // {src, edge id}
    }
}

// ---------------- weight fake-quant + a_edge projection vectors ----------------
// block 0: layer 1, block 1: layer 2
__global__ void k_weights(const float* W1, const float* W2,
                          const float* We1, const float* ae1,
                          const float* We2, const float* ae2,
                          float* Wq1, float* Wq2, float* v1, float* v2) {
    __shared__ float red[256];
    int t = threadIdx.x;
    const float* W  = blockIdx.x ? W2 : W1;
    const float* We = blockIdx.x ? We2 : We1;
    const float* ae = blockIdx.x ? ae2 : ae1;
    float* Wq = blockIdx.x ? Wq2 : Wq1;
    float* v  = blockIdx.x ? v2 : v1;
    float m = 0.0f;
    for (int i = t; i < 8192; i += 256) m = fmaxf(m, fabsf(W[i]));
    red[t] = m; __syncthreads();
    for (int s = 128; s > 0; s >>= 1) { if (t < s) red[t] = fmaxf(red[t], red[t + s]); __syncthreads(); }
    float s1 = fmaxf(red[0], 1e-8f) / 127.0f;
    __syncthreads();
    for (int i = t; i < 8192; i += 256) Wq[i] = quantize(W[i], s1);
    if (t < 64) {
        int h = t >> 5, d = t & 31;
        float acc = 0.0f;
        for (int c = 0; c < 64; ++c) acc += We[(h * 64 + c) * 32 + d] * ae[h * 64 + c];
        v[t] = acc;
    }
}

// ---------------- a_edge for both layers, edge order (fully coalesced) ----------------
__global__ void k_aedge(const float* edge_attr, const float* v1, const float* v2,
                        float2* ae1e, float2* ae2e) {
    __shared__ float vs[128];
    int t = threadIdx.x;
    if (t < 64) vs[t] = v1[t];
    else if (t < 128) vs[t] = v2[t - 64];
    __syncthreads();
    int e = blockIdx.x * 256 + t;
    if (e >= EE) return;
    const float4* ea = (const float4*)(edge_attr + (size_t)e * 32);
    float a00 = 0, a01 = 0, a10 = 0, a11 = 0;
#pragma unroll
    for (int q = 0; q < 8; ++q) {
        float4 w = ea[q];
        float xs4[4] = {w.x, w.y, w.z, w.w};
#pragma unroll
        for (int j = 0; j < 4; ++j) {
            int d = q * 4 + j;
            a00 += xs4[j] * vs[d];
            a01 += xs4[j] * vs[32 + d];
            a10 += xs4[j] * vs[64 + d];
            a11 += xs4[j] * vs[96 + d];
        }
    }
    ae1e[e] = make_float2(a00, a01);
    ae2e[e] = make_float2(a10, a11);
}

// ---------------- h = f(in) @ Wq.T (+ a_src/a_dst dots), h stored fp16 ----------------
// Wave = (head, 16-node group): lane l holds ONLY weight row head*64+l (16 float4 = 64 VGPR).
// Results staged in LDS, then packed to __half2 {head0,head1} with coalesced stores.
// slots==nullptr: f = rn-scale (layer 1).  slots!=nullptr: f = rn2*relu(quant(v,s1)) (layer 2).
__global__ void __launch_bounds__(256, 4)
k_hproj(const float* __restrict__ in, const float* __restrict__ rn,
        const unsigned* __restrict__ slots,
        const float* __restrict__ Wq,
        const float* __restrict__ att_s, const float* __restrict__ att_d,
        __half2* __restrict__ hp, float* __restrict__ asrcv,
        float* __restrict__ adstv) {
    __shared__ float xs[32][64];     // 8 KB staged inputs
    __shared__ float hres[32][128];  // 16 KB fp32 results
    __shared__ unsigned redu[256];
    int t = threadIdx.x;
    float qs = 0.0f;
    if (slots) {   // fused absmax-slot reduction -> s1
        redu[t] = slots[t]; __syncthreads();
        for (int s = 128; s > 0; s >>= 1) {
            if (t < s) redu[t] = (redu[t] > redu[t + s]) ? redu[t] : redu[t + s];
            __syncthreads();
        }
        qs = fmaxf(__uint_as_float(redu[0]), 1e-8f) / 127.0f;
        __syncthreads();
    }
    int node0 = blockIdx.x * 32;
    for (int i = t; i < 512; i += 256) {
        int n = i >> 4, c4 = i & 15;
        int node = node0 + n;
        float4 v = make_float4(0.f, 0.f, 0.f, 0.f);
        if (node < NN) {
            v = ((const float4*)(in + (size_t)node * 64))[c4];
            float r = rn[node];
            if (slots) {
                v.x = fmaxf(quantize(v.x, qs), 0.f) * r;
                v.y = fmaxf(quantize(v.y, qs), 0.f) * r;
                v.z = fmaxf(quantize(v.z, qs), 0.f) * r;
                v.w = fmaxf(quantize(v.w, qs), 0.f) * r;
            } else {
                v.x *= r; v.y *= r; v.z *= r; v.w *= r;
            }
        }
        ((float4*)xs[n])[c4] = v;
    }
    int w = t >> 6, l = t & 63;
    int head = w & 1, ns = (w >> 1) * 16;
    int orow = head * 64 + l;
    float4 wr[16];
    const float4* wp = (const float4*)(Wq + (size_t)orow * 64);
#pragma unroll
    for (int q = 0; q < 16; ++q) wr[q] = wp[q];
    float ats = att_s[orow], atd = att_d[orow];
    __syncthreads();
    for (int nn = 0; nn < 16; ++nn) {
        int nl = ns + nn;
        int node = node0 + nl;
        const float4* xr = (const float4*)xs[nl];
        float a = 0.0f;
#pragma unroll
        for (int q = 0; q < 16; ++q) {
            float4 xv = xr[q];             // uniform address -> LDS broadcast
            float4 wv = wr[q];
            a += xv.x * wv.x + xv.y * wv.y + xv.z * wv.z + xv.w * wv.w;
        }
        hres[nl][orow] = a;
        float ps = a * ats, pd = a * atd;
#pragma unroll
        for (int m = 32; m > 0; m >>= 1) {
            ps += __shfl_xor(ps, m, 64);
            pd += __shfl_xor(pd, m, 64);
        }
        if (l == 0 && node < NN) {
            asrcv[(size_t)node * 2 + head] = ps;
            adstv[(size_t)node * 2 + head] = pd;
        }
    }
    __syncthreads();
    // pack fp32 LDS results -> interleaved __half2, coalesced stores
    for (int i = t; i < 2048; i += 256) {
        int nl = i >> 6, c = i & 63;
        int node = node0 + nl;
        if (node < NN)
            hp[(size_t)node * 64 + c] = __floats2half2_rn(hres[nl][c], hres[nl][64 + c]);
    }
}

// ---------------- fused softmax+aggregate: wave per dst node ----------------
// Phase 1 (lane-parallel): lanes l<deg read sp (coalesced), gather aee[edge] + asrcv[src],
//                          compute p = exp(leaky(.)) once per edge.
// Phase 2 (broadcast): readlane (src, p); 8 independent fp16 hp-row gathers per group.
// Per-node absmax written as a PLAIN STORE (no hot atomics).
__global__ void k_aggregate(const unsigned* __restrict__ off, const uint2* __restrict__ sp,
                            const float2* __restrict__ aee,
                            const float2* __restrict__ asrcv, const float2* __restrict__ adstv,
                            const __half2* __restrict__ hp, const float* __restrict__ bias,
                            float* __restrict__ outp, float* __restrict__ amax_node) {
    int t = threadIdx.x;
    int l = t & 63;
    int node = blockIdx.x * 4 + (t >> 6);
    if (node >= NN) return;
    unsigned s0 = off[node], e0 = off[node + 1];
    float2 adv = adstv[node];
    float bl = bias[l];
    float acc0 = 0.f, acc1 = 0.f, psum0 = 0.f, psum1 = 0.f;
    for (unsigned base = s0; base < e0; base += 64) {
        int cnt = (int)min(64u, e0 - base);
        float p0 = 0.f, p1 = 0.f;
        unsigned s = 0u;
        if (l < cnt) {
            uint2 se = sp[base + l];             // coalesced {src, edge}
            s = se.x;
            float2 ev = aee[se.y];               // parallel 8B gather (L2/L3-resident 6.4MB)
            float2 av = asrcv[s];                // parallel 8B gather (800KB)
            p0 = __expf(leaky(av.x + adv.x + ev.x));
            p1 = __expf(leaky(av.y + adv.y + ev.y));
        }
        psum0 += p0; psum1 += p1;
        int su = (int)s;
        unsigned pu0 = __float_as_uint(p0), pu1 = __float_as_uint(p1);
        for (int j = 0; j < cnt; j += 8) {
            float2 f[8]; float q0[8], q1[8];
#pragma unroll
            for (int k = 0; k < 8; ++k) {
                unsigned sk = (unsigned)__builtin_amdgcn_readlane(su, j + k);
                __half2 h = hp[(size_t)sk * 64 + l];
                f[k] = __half22float2(h);
                q0[k] = __uint_as_float((unsigned)__builtin_amdgcn_readlane((int)pu0, j + k));
                q1[k] = __uint_as_float((unsigned)__builtin_amdgcn_readlane((int)pu1, j + k));
            }
#pragma unroll
            for (int k = 0; k < 8; ++k) {
                acc0 = fmaf(q0[k], f[k].x, acc0);
                acc1 = fmaf(q1[k], f[k].y, acc1);
            }
        }
    }
#pragma unroll
    for (int m = 32; m > 0; m >>= 1) {
        psum0 += __shfl_xor(psum0, m, 64);
        psum1 += __shfl_xor(psum1, m, 64);
    }
    float o = 0.5f * (acc0 / (psum0 + 1e-16f) + acc1 / (psum1 + 1e-16f)) + bl;
    outp[(size_t)node * 64 + l] = o;
    float v = fabsf(o);
#pragma unroll
    for (int m = 32; m > 0; m >>= 1) v = fmaxf(v, __shfl_xor(v, m, 64));
    if (l == 0) amax_node[node] = v;          // plain store, zero contention
}

// ---------------- per-node absmax -> 256 partial slots (no atomics) ----------------
__global__ void k_amax_partial(const float* __restrict__ amax_node, unsigned* __restrict__ slots) {
    __shared__ float red[256];
    int t = threadIdx.x;
    float m = 0.0f;
    for (int i = blockIdx.x * 256 + t; i < NN; i += 256 * 256)
        m = fmaxf(m, amax_node[i]);
    red[t] = m; __syncthreads();
    for (int s = 128; s > 0; s >>= 1) {
        if (t < s) red[t] = fmaxf(red[t], red[t + s]);
        __syncthreads();
    }
    if (t == 0) slots[blockIdx.x] = __float_as_uint(red[0]);  // own slot, no contention
}

// ---------------- final output fake-quant in place (fused slot reduce) ----------------
__global__ void k_quant_out(float* buf, const unsigned* slots) {
    __shared__ unsigned red[256];
    int t = threadIdx.x;
    red[t] = slots[t]; __syncthreads();
    for (int s = 128; s > 0; s >>= 1) {
        if (t < s) red[t] = (red[t] > red[t + s]) ? red[t] : red[t + s];
        __syncthreads();
    }
    float s2 = fmaxf(__uint_as_float(red[0]), 1e-8f) / 127.0f;
    int i = blockIdx.x * 256 + t;
    if (i < NN * 64) buf[i] = quantize(buf[i], s2);
}

extern "C" void kernel_launch(void* const* d_in, const int* in_sizes, int n_in,
                              void* d_out, int out_size, void* d_ws, size_t ws_size,
                              hipStream_t stream) {
    const float* x     = (const float*)d_in[0];
    const int*   ei    = (const int*)d_in[1];
    const float* eattr = (const float*)d_in[2];
    const float* a1    = (const float*)d_in[3];
    const float* W1    = (const float*)d_in[4];
    const float* We1   = (const float*)d_in[5];
    const float* as1   = (const float*)d_in[6];
    const float* ad1   = (const float*)d_in[7];
    const float* ae1   = (const float*)d_in[8];
    const float* b1    = (const float*)d_in[9];
    const float* a2    = (const float*)d_in[10];
    const float* W2    = (const float*)d_in[11];
    const float* We2   = (const float*)d_in[12];
    const float* as2   = (const float*)d_in[13];
    const float* ad2   = (const float*)d_in[14];
    const float* ae2   = (const float*)d_in[15];
    const float* b2    = (const float*)d_in[16];
    float* out = (float*)d_out;

    char* w = (char*)d_ws;
    size_t o = 0;
    auto alloc = [&](size_t bytes) -> char* {
        char* p = w + o;
        o += (bytes + 255) & ~(size_t)255;
        return p;
    };
    unsigned* deg_src  = (unsigned*)alloc((size_t)NN * 4);
    unsigned* deg_dst  = (unsigned*)alloc((size_t)NN * 4);
    unsigned* offs     = (unsigned*)alloc((size_t)(NN + 1) * 4);
    unsigned* cursor   = (unsigned*)alloc((size_t)NN * 4);
    unsigned* chunkSum = (unsigned*)alloc((size_t)NCH * 4);
    unsigned* chunkOff = (unsigned*)alloc((size_t)NCH * 4);
    uint2*    sp       = (uint2*)alloc((size_t)EE * 8);
    float2*   ae1e     = (float2*)alloc((size_t)EE * 8);
    float2*   ae2e     = (float2*)alloc((size_t)EE * 8);
    float2*   asrcv    = (float2*)alloc((size_t)NN * 8);
    float2*   adstv    = (float2*)alloc((size_t)NN * 8);
    __half2*  hp       = (__half2*)alloc((size_t)NN * 64 * 4);
    float*    mid      = (float*)alloc((size_t)NN * 64 * 4);
    float*    rn1      = (float*)alloc((size_t)NN * 4);
    float*    rn2      = (float*)alloc((size_t)NN * 4);
    float*    amaxn    = (float*)alloc((size_t)NN * 4);
    float*    Wq1      = (float*)alloc(8192 * 4);
    float*    Wq2      = (float*)alloc(8192 * 4);
    float*    v1       = (float*)alloc(64 * 4);
    float*    v2       = (float*)alloc(64 * 4);
    unsigned* slots1   = (unsigned*)alloc(256 * 4);
    unsigned* slots2   = (unsigned*)alloc(256 * 4);

    dim3 B(256);
    k_init<<<391, B, 0, stream>>>(deg_src, deg_dst);
    k_deg<<<3125, B, 0, stream>>>(ei, deg_src, deg_dst);
    k_scan_chunksum<<<NCH, B, 0, stream>>>(deg_dst, chunkSum);
    k_scan_chunkoff<<<1, B, 0, stream>>>(chunkSum, chunkOff, offs);
    k_scan_final<<<NCH, B, 0, stream>>>(deg_dst, chunkOff, offs, cursor,
                                        deg_src, a1, a2, rn1, rn2);
    k_scatter<<<3125, B, 0, stream>>>(ei, cursor, sp);
    k_weights<<<2, B, 0, stream>>>(W1, W2, We1, ae1, We2, ae2, Wq1, Wq2, v1, v2);
    k_aedge<<<3125, B, 0, stream>>>(eattr, v1, v2, ae1e, ae2e);
    // layer 1
    k_hproj<<<3125, B, 0, stream>>>(x, rn1, nullptr, Wq1, as1, ad1, hp,
                                    (float*)asrcv, (float*)adstv);
    k_aggregate<<<25000, B, 0, stream>>>(offs, sp, ae1e, asrcv, adstv, hp, b1, mid, amaxn);
    k_amax_partial<<<256, B, 0, stream>>>(amaxn, slots1);
    // layer 2 (quant+relu+rnorm fused into hproj staging)
    k_hproj<<<3125, B, 0, stream>>>(mid, rn2, slots1, Wq2, as2, ad2, hp,
                                    (float*)asrcv, (float*)adstv);
    k_aggregate<<<25000, B, 0, stream>>>(offs, sp, ae2e, asrcv, adstv, hp, b2, out, amaxn);
    k_amax_partial<<<256, B, 0, stream>>>(amaxn, slots2);
    k_quant_out<<<25000, B, 0, stream>>>(out, slots2);
}